// Round 1
// baseline (1717.497 us; speedup 1.0000x reference)
//
#include <hip/hip_runtime.h>

// ---------------------------------------------------------------------------
// GCN (2-branch) + GAP + MLP head, fp32, MI355X.
// Strategy: CSR-by-dst built once per call; aggregate in INPUT feature space
// (agg and GEMM commute), then fused GEMM+bias+ReLU per layer.
// ---------------------------------------------------------------------------

static inline size_t align256(size_t x) { return (x + 255) & ~size_t(255); }

// ---------------- degree ----------------
__global__ void deg_kernel(const int* __restrict__ dst, const float* __restrict__ w,
                           int E, int* __restrict__ cnt, float* __restrict__ degw) {
    int i = blockIdx.x * blockDim.x + threadIdx.x;
    int stride = gridDim.x * blockDim.x;
    for (int e = i; e < E; e += stride) {
        int d = dst[e];
        atomicAdd(&cnt[d], 1);
        atomicAdd(&degw[d], w[e]);
    }
}

__global__ void dinv_kernel(const float* __restrict__ degw, int N,
                            float* __restrict__ dinv, float* __restrict__ dinv2) {
    int i = blockIdx.x * blockDim.x + threadIdx.x;
    if (i < N) {
        float d = 1.0f + degw[i];
        float r = rsqrtf(d);
        dinv[i] = r;
        dinv2[i] = r * r;
    }
}

// ---------------- exclusive prefix sum (single block, wave scans) ----------------
__global__ void scan_kernel(const int* __restrict__ cnt, int n, int* __restrict__ rp) {
    __shared__ int wsum[16];
    __shared__ int carry_s;
    int t = threadIdx.x;              // 1024 threads
    int wave = t >> 6, lane = t & 63;
    if (t == 0) carry_s = 0;
    __syncthreads();
    for (int base = 0; base < n; base += 1024) {
        int i = base + t;
        int v = (i < n) ? cnt[i] : 0;
        int x = v;
        #pragma unroll
        for (int off = 1; off < 64; off <<= 1) {
            int y = __shfl_up(x, off, 64);
            if (lane >= off) x += y;
        }
        if (lane == 63) wsum[wave] = x;
        __syncthreads();
        if (wave == 0 && lane < 16) {
            int s = wsum[lane];
            #pragma unroll
            for (int off = 1; off < 16; off <<= 1) {
                int y = __shfl_up(s, off, 64);
                if (lane >= off) s += y;
            }
            wsum[lane] = s;  // inclusive wave sums
        }
        __syncthreads();
        int wexcl = (wave == 0) ? 0 : wsum[wave - 1];
        int incl = wexcl + x;
        if (i < n) rp[i] = carry_s + incl - v;  // exclusive
        __syncthreads();
        if (t == 1023) carry_s += wsum[15];
        __syncthreads();
    }
    if (t == 0) rp[n] = carry_s;
}

// ---------------- CSR fill ----------------
__global__ void fill_csr(const int* __restrict__ src, const int* __restrict__ dst,
                         const float* __restrict__ w, int E,
                         const float* __restrict__ dinv, const int* __restrict__ rp,
                         int* __restrict__ cursor,
                         int* __restrict__ csr_src, float* __restrict__ csr_norm) {
    int i = blockIdx.x * blockDim.x + threadIdx.x;
    int stride = gridDim.x * blockDim.x;
    for (int e = i; e < E; e += stride) {
        int d = dst[e], s = src[e];
        int pos = atomicAdd(&cursor[d], 1);
        int idx = rp[d] + pos;
        csr_src[idx] = s;
        csr_norm[idx] = w[e] * dinv[s] * dinv[d];
    }
}

// ---------------- aggregation: z[n] = dinv2[n]*h[n] + sum_in norm*h[src] ----------------
// LANES = F/4 threads per node, float4 per thread.
template <int LANES>
__global__ void aggregate_kernel(const float* __restrict__ h, int N,
                                 const int* __restrict__ rp,
                                 const int* __restrict__ csr_src,
                                 const float* __restrict__ csr_norm,
                                 const float* __restrict__ dinv2,
                                 float* __restrict__ z) {
    constexpr int GPB = 256 / LANES;
    int group = threadIdx.x / LANES;
    int lane = threadIdx.x % LANES;
    int n = blockIdx.x * GPB + group;
    if (n >= N) return;
    const float4* h4 = (const float4*)h;
    float4 self = h4[(size_t)n * LANES + lane];
    float d2 = dinv2[n];
    float4 acc;
    acc.x = self.x * d2; acc.y = self.y * d2; acc.z = self.z * d2; acc.w = self.w * d2;
    int e = rp[n], end = rp[n + 1];
    // 4-deep unroll for gather ILP
    for (; e + 3 < end; e += 4) {
        int s0 = csr_src[e], s1 = csr_src[e + 1], s2 = csr_src[e + 2], s3 = csr_src[e + 3];
        float n0 = csr_norm[e], n1 = csr_norm[e + 1], n2 = csr_norm[e + 2], n3 = csr_norm[e + 3];
        float4 v0 = h4[(size_t)s0 * LANES + lane];
        float4 v1 = h4[(size_t)s1 * LANES + lane];
        float4 v2 = h4[(size_t)s2 * LANES + lane];
        float4 v3 = h4[(size_t)s3 * LANES + lane];
        acc.x += n0 * v0.x + n1 * v1.x + n2 * v2.x + n3 * v3.x;
        acc.y += n0 * v0.y + n1 * v1.y + n2 * v2.y + n3 * v3.y;
        acc.z += n0 * v0.z + n1 * v1.z + n2 * v2.z + n3 * v3.z;
        acc.w += n0 * v0.w + n1 * v1.w + n2 * v2.w + n3 * v3.w;
    }
    for (; e < end; e++) {
        int s = csr_src[e];
        float nm = csr_norm[e];
        float4 v = h4[(size_t)s * LANES + lane];
        acc.x += nm * v.x; acc.y += nm * v.y; acc.z += nm * v.z; acc.w += nm * v.w;
    }
    float4* z4 = (float4*)z;
    z4[(size_t)n * LANES + lane] = acc;
}

// ---------------- GEMM: H[N,128] = relu(Z[N,K] @ W[K,128] + b) ----------------
// 64-row tile, K-tile 32; W-tile + padded Z-tile in LDS; 8 rows x 4 cols / thread.
#define BM 64
#define BK 32
__global__ __launch_bounds__(256) void gemm_bias_relu(
    const float* __restrict__ Z, const float* __restrict__ W,
    const float* __restrict__ bias, float* __restrict__ H, int N, int K) {
    __shared__ __attribute__((aligned(16))) float Wt[BK * 128];
    __shared__ __attribute__((aligned(16))) float Zt[BM * 36];  // +4 pad: breaks bank aliasing
    int tid = threadIdx.x;
    int row0 = blockIdx.x * BM;
    int j0 = (tid & 31) * 4;
    int r0 = (tid >> 5) * 8;
    float4 acc[8];
    #pragma unroll
    for (int r = 0; r < 8; r++) acc[r] = make_float4(0.f, 0.f, 0.f, 0.f);

    for (int kt = 0; kt < K; kt += BK) {
        // load W tile: 32x128 floats = 1024 float4 = 256 threads * 4
        #pragma unroll
        for (int i = 0; i < 4; i++) {
            int fid = tid + i * 256;
            int kr = fid >> 5;
            int jc = fid & 31;
            float4 wv = *(const float4*)&W[(size_t)(kt + kr) * 128 + jc * 4];
            *(float4*)&Wt[kr * 128 + jc * 4] = wv;
        }
        // load Z tile: 64x32 floats = 512 float4 = 256 threads * 2
        #pragma unroll
        for (int i = 0; i < 2; i++) {
            int fid = tid + i * 256;
            int r = fid >> 3;
            int c = fid & 7;
            int gr = row0 + r;
            float4 zv = make_float4(0.f, 0.f, 0.f, 0.f);
            if (gr < N) zv = *(const float4*)&Z[(size_t)gr * K + kt + c * 4];
            *(float4*)&Zt[r * 36 + c * 4] = zv;
        }
        __syncthreads();
        #pragma unroll
        for (int kk = 0; kk < BK; kk++) {
            float4 wv = *(const float4*)&Wt[kk * 128 + j0];
            #pragma unroll
            for (int rr = 0; rr < 8; rr++) {
                float zv = Zt[(r0 + rr) * 36 + kk];
                acc[rr].x += zv * wv.x;
                acc[rr].y += zv * wv.y;
                acc[rr].z += zv * wv.z;
                acc[rr].w += zv * wv.w;
            }
        }
        __syncthreads();
    }
    float4 bv = *(const float4*)&bias[j0];
    #pragma unroll
    for (int rr = 0; rr < 8; rr++) {
        int gr = row0 + r0 + rr;
        if (gr < N) {
            float4 o;
            o.x = fmaxf(acc[rr].x + bv.x, 0.f);
            o.y = fmaxf(acc[rr].y + bv.y, 0.f);
            o.z = fmaxf(acc[rr].z + bv.z, 0.f);
            o.w = fmaxf(acc[rr].w + bv.w, 0.f);
            *(float4*)&H[(size_t)gr * 128 + j0] = o;
        }
    }
}

// ---------------- pooling: one block per graph, binary search sorted batch ----------------
__device__ inline int lower_bound(const int* __restrict__ a, int n, int v) {
    int lo = 0, hi = n;
    while (lo < hi) {
        int m = (lo + hi) >> 1;
        if (a[m] < v) lo = m + 1; else hi = m;
    }
    return lo;
}

__global__ void pool_kernel(const float* __restrict__ hL, const float* __restrict__ hS,
                            const int* __restrict__ batchL, int NL,
                            const int* __restrict__ batchS, int NS,
                            float* __restrict__ pool) {
    int g = blockIdx.x;
    int f = threadIdx.x;  // 128
    int sL = lower_bound(batchL, NL, g), eL = lower_bound(batchL, NL, g + 1);
    int sS = lower_bound(batchS, NS, g), eS = lower_bound(batchS, NS, g + 1);
    float acc = 0.f;
    for (int n = sL; n < eL; n++) acc += hL[(size_t)n * 128 + f];
    for (int n = sS; n < eS; n++) acc += hS[(size_t)n * 128 + f];
    int cnt = (eL - sL) + (eS - sS);
    float c = (float)(cnt > 0 ? cnt : 1);
    pool[g * 128 + f] = acc / c;
}

// ---------------- MLP head: lin1 -> lin2 -> BN(eval) -> relu -> out ----------------
__global__ void mlp_kernel(const float* __restrict__ pool,
                           const float* __restrict__ W1, const float* __restrict__ b1,
                           const float* __restrict__ W2, const float* __restrict__ b2,
                           const float* __restrict__ gamma, const float* __restrict__ beta,
                           const float* __restrict__ outW, const float* __restrict__ outb,
                           float* __restrict__ d_out) {
    __shared__ float row[128];
    __shared__ float row2[128];
    int g = blockIdx.x, t = threadIdx.x;  // 128 threads
    row[t] = pool[g * 128 + t];
    __syncthreads();
    float a = b1[t];
    #pragma unroll 4
    for (int k = 0; k < 128; k++) a += row[k] * W1[k * 128 + t];
    row2[t] = a;  // NOTE: no relu between lin1 and lin2 in reference
    __syncthreads();
    if (t < 64) {
        float a2 = b2[t];
        #pragma unroll 4
        for (int k = 0; k < 128; k++) a2 += row2[k] * W2[k * 64 + t];
        float rs = rsqrtf(1.0f + 1e-5f);
        float hb = a2 * rs * gamma[t] + beta[t];
        float hr = fmaxf(hb, 0.f);
        d_out[512 + g * 64 + t] = hr;
        float p = hr * outW[t];
        #pragma unroll
        for (int off = 32; off > 0; off >>= 1) p += __shfl_down(p, off, 64);
        if (t == 0) d_out[g] = p + outb[0];
    }
}

// ---------------------------------------------------------------------------
extern "C" void kernel_launch(void* const* d_in, const int* in_sizes, int n_in,
                              void* d_out, int out_size, void* d_ws, size_t ws_size,
                              hipStream_t stream) {
    const float* x_l = (const float*)d_in[0];
    const int*   ei_l = (const int*)d_in[1];
    const float* w_l = (const float*)d_in[2];
    const float* x_s = (const float*)d_in[3];
    const int*   ei_s = (const int*)d_in[4];
    const float* w_s = (const float*)d_in[5];
    const int*   batch_l = (const int*)d_in[6];
    const int*   batch_s = (const int*)d_in[7];

    const int NL = in_sizes[6];           // 100000
    const int NS = in_sizes[7];           // 50000
    const int EL = in_sizes[2];           // 1600000
    const int ES = in_sizes[5];           // 800000

    const float* Wa[4] = {(const float*)d_in[8],  (const float*)d_in[12],
                          (const float*)d_in[16], (const float*)d_in[20]};
    const float* ba[4] = {(const float*)d_in[9],  (const float*)d_in[13],
                          (const float*)d_in[17], (const float*)d_in[21]};
    const float* Wb[4] = {(const float*)d_in[10], (const float*)d_in[14],
                          (const float*)d_in[18], (const float*)d_in[22]};
    const float* bb[4] = {(const float*)d_in[11], (const float*)d_in[15],
                          (const float*)d_in[19], (const float*)d_in[23]};
    const float* lin1_W = (const float*)d_in[24];
    const float* lin1_b = (const float*)d_in[25];
    const float* lin2_W = (const float*)d_in[26];
    const float* lin2_b = (const float*)d_in[27];
    const float* bn_g = (const float*)d_in[28];
    const float* bn_b = (const float*)d_in[29];
    const float* out_W = (const float*)d_in[30];
    const float* out_b = (const float*)d_in[31];
    float* out = (float*)d_out;

    const int* src_l = ei_l;            // edge_index[0]
    const int* dst_l = ei_l + EL;       // edge_index[1]
    const int* src_s = ei_s;
    const int* dst_s = ei_s + ES;

    // ---- workspace carve ----
    char* p = (char*)d_ws;
    auto alloc = [&](size_t bytes) { char* r = p; p += align256(bytes); return r; };
    float* A_l = (float*)alloc((size_t)NL * 128 * 4);
    float* B_l = (float*)alloc((size_t)NL * 128 * 4);
    float* A_s = (float*)alloc((size_t)NS * 128 * 4);
    float* B_s = (float*)alloc((size_t)NS * 128 * 4);
    int*   csr_src_l  = (int*)alloc((size_t)EL * 4);
    float* csr_norm_l = (float*)alloc((size_t)EL * 4);
    int*   csr_src_s  = (int*)alloc((size_t)ES * 4);
    float* csr_norm_s = (float*)alloc((size_t)ES * 4);
    int*   rp_l  = (int*)alloc((size_t)(NL + 1) * 4);
    int*   rp_s  = (int*)alloc((size_t)(NS + 1) * 4);
    int*   cnt_l = (int*)alloc((size_t)NL * 4);
    int*   cnt_s = (int*)alloc((size_t)NS * 4);
    float* degw_l = (float*)alloc((size_t)NL * 4);
    float* degw_s = (float*)alloc((size_t)NS * 4);
    float* dinv_l  = (float*)alloc((size_t)NL * 4);
    float* dinv2_l = (float*)alloc((size_t)NL * 4);
    float* dinv_s  = (float*)alloc((size_t)NS * 4);
    float* dinv2_s = (float*)alloc((size_t)NS * 4);
    float* pool = (float*)alloc((size_t)512 * 128 * 4);
    (void)ws_size; (void)n_in; (void)out_size;

    // ---- degree / dinv ----
    hipMemsetAsync(cnt_l, 0, (size_t)NL * 4, stream);
    hipMemsetAsync(cnt_s, 0, (size_t)NS * 4, stream);
    hipMemsetAsync(degw_l, 0, (size_t)NL * 4, stream);
    hipMemsetAsync(degw_s, 0, (size_t)NS * 4, stream);
    deg_kernel<<<2048, 256, 0, stream>>>(dst_l, w_l, EL, cnt_l, degw_l);
    deg_kernel<<<2048, 256, 0, stream>>>(dst_s, w_s, ES, cnt_s, degw_s);
    dinv_kernel<<<(NL + 255) / 256, 256, 0, stream>>>(degw_l, NL, dinv_l, dinv2_l);
    dinv_kernel<<<(NS + 255) / 256, 256, 0, stream>>>(degw_s, NS, dinv_s, dinv2_s);

    // ---- CSR ----
    scan_kernel<<<1, 1024, 0, stream>>>(cnt_l, NL, rp_l);
    scan_kernel<<<1, 1024, 0, stream>>>(cnt_s, NS, rp_s);
    hipMemsetAsync(cnt_l, 0, (size_t)NL * 4, stream);  // reuse as cursor
    hipMemsetAsync(cnt_s, 0, (size_t)NS * 4, stream);
    fill_csr<<<2048, 256, 0, stream>>>(src_l, dst_l, w_l, EL, dinv_l, rp_l, cnt_l,
                                       csr_src_l, csr_norm_l);
    fill_csr<<<2048, 256, 0, stream>>>(src_s, dst_s, w_s, ES, dinv_s, rp_s, cnt_s,
                                       csr_src_s, csr_norm_s);

    // ---- large branch: layer 0 (F_in=64), layers 1-3 (F_in=128) ----
    aggregate_kernel<16><<<(NL + 15) / 16, 256, 0, stream>>>(
        x_l, NL, rp_l, csr_src_l, csr_norm_l, dinv2_l, B_l);
    gemm_bias_relu<<<(NL + BM - 1) / BM, 256, 0, stream>>>(B_l, Wa[0], ba[0], A_l, NL, 64);
    for (int layer = 1; layer < 4; layer++) {
        aggregate_kernel<32><<<(NL + 7) / 8, 256, 0, stream>>>(
            A_l, NL, rp_l, csr_src_l, csr_norm_l, dinv2_l, B_l);
        gemm_bias_relu<<<(NL + BM - 1) / BM, 256, 0, stream>>>(B_l, Wa[layer], ba[layer],
                                                               A_l, NL, 128);
    }

    // ---- small branch: layer 0 (F_in=32), layers 1-3 (F_in=128) ----
    aggregate_kernel<8><<<(NS + 31) / 32, 256, 0, stream>>>(
        x_s, NS, rp_s, csr_src_s, csr_norm_s, dinv2_s, B_s);
    gemm_bias_relu<<<(NS + BM - 1) / BM, 256, 0, stream>>>(B_s, Wb[0], bb[0], A_s, NS, 32);
    for (int layer = 1; layer < 4; layer++) {
        aggregate_kernel<32><<<(NS + 7) / 8, 256, 0, stream>>>(
            A_s, NS, rp_s, csr_src_s, csr_norm_s, dinv2_s, B_s);
        gemm_bias_relu<<<(NS + BM - 1) / BM, 256, 0, stream>>>(B_s, Wb[layer], bb[layer],
                                                               A_s, NS, 128);
    }

    // ---- pooling + head ----
    pool_kernel<<<512, 128, 0, stream>>>(A_l, A_s, batch_l, NL, batch_s, NS, pool);
    mlp_kernel<<<512, 128, 0, stream>>>(pool, lin1_W, lin1_b, lin2_W, lin2_b,
                                        bn_g, bn_b, out_W, out_b, out);
}

// Round 2
// 1458.198 us; speedup vs baseline: 1.1778x; 1.1778x over previous
//
#include <hip/hip_runtime.h>

// ---------------------------------------------------------------------------
// GCN (2-branch) + GAP + MLP head, fp32, MI355X.
// R1: CSR build overhaul — count-only atomics (degw via post-fill row sum),
// packed int2{src,w} edge records, factored norm (w*dinv[src] stored per edge,
// dinv[dst] applied in aggregate epilogue), 3-phase scan.
// ---------------------------------------------------------------------------

static inline size_t align256(size_t x) { return (x + 255) & ~size_t(255); }

// ---------------- count incoming edges (1 atomic/edge) ----------------
__global__ void count_kernel(const int* __restrict__ dst, int E, int* __restrict__ cnt) {
    int i = blockIdx.x * blockDim.x + threadIdx.x;
    int stride = gridDim.x * blockDim.x;
    for (int e = i; e < E; e += stride) atomicAdd(&cnt[dst[e]], 1);
}

// ---------------- 3-phase exclusive scan ----------------
// phase 1: per-block (1024 elems = 256 thr x 4) exclusive scan into rp, block total to btot
__global__ __launch_bounds__(256) void scan_block(const int* __restrict__ cnt, int n,
                                                  int* __restrict__ rp, int* __restrict__ btot) {
    __shared__ int wsum[4];
    int b = blockIdx.x, t = threadIdx.x;
    int wave = t >> 6, lane = t & 63;
    int base = b * 1024 + t * 4;
    int v0 = (base + 0 < n) ? cnt[base + 0] : 0;
    int v1 = (base + 1 < n) ? cnt[base + 1] : 0;
    int v2 = (base + 2 < n) ? cnt[base + 2] : 0;
    int v3 = (base + 3 < n) ? cnt[base + 3] : 0;
    int tsum = v0 + v1 + v2 + v3;
    int x = tsum;
    #pragma unroll
    for (int off = 1; off < 64; off <<= 1) {
        int y = __shfl_up(x, off, 64);
        if (lane >= off) x += y;
    }
    if (lane == 63) wsum[wave] = x;
    __syncthreads();
    int woff = 0;
    #pragma unroll
    for (int i = 0; i < 3; i++) if (wave > i) woff += wsum[i];
    int texcl = woff + x - tsum;
    if (base + 0 < n) rp[base + 0] = texcl;
    if (base + 1 < n) rp[base + 1] = texcl + v0;
    if (base + 2 < n) rp[base + 2] = texcl + v0 + v1;
    if (base + 3 < n) rp[base + 3] = texcl + v0 + v1 + v2;
    if (t == 255) btot[b] = woff + x;
}

// phase 2: single block scans nb (<=1024) block totals; boff[nb] = grand total
__global__ __launch_bounds__(256) void scan_tot(const int* __restrict__ btot, int nb,
                                                int* __restrict__ boff) {
    __shared__ int wsum[4];
    int t = threadIdx.x;
    int wave = t >> 6, lane = t & 63;
    int base = t * 4;
    int v0 = (base + 0 < nb) ? btot[base + 0] : 0;
    int v1 = (base + 1 < nb) ? btot[base + 1] : 0;
    int v2 = (base + 2 < nb) ? btot[base + 2] : 0;
    int v3 = (base + 3 < nb) ? btot[base + 3] : 0;
    int tsum = v0 + v1 + v2 + v3;
    int x = tsum;
    #pragma unroll
    for (int off = 1; off < 64; off <<= 1) {
        int y = __shfl_up(x, off, 64);
        if (lane >= off) x += y;
    }
    if (lane == 63) wsum[wave] = x;
    __syncthreads();
    int woff = 0;
    #pragma unroll
    for (int i = 0; i < 3; i++) if (wave > i) woff += wsum[i];
    int texcl = woff + x - tsum;
    if (base + 0 < nb) boff[base + 0] = texcl;
    if (base + 1 < nb) boff[base + 1] = texcl + v0;
    if (base + 2 < nb) boff[base + 2] = texcl + v0 + v1;
    if (base + 3 < nb) boff[base + 3] = texcl + v0 + v1 + v2;
    if (t == 255) boff[nb] = woff + x;
}

// phase 3: add block offsets in place; write rp[n] = E
__global__ void scan_add(int* __restrict__ rp, int n, const int* __restrict__ boff, int nb) {
    int i = blockIdx.x * blockDim.x + threadIdx.x;
    if (i < n) rp[i] += boff[i >> 10];
    if (i == 0) rp[n] = boff[nb];
}

// ---------------- CSR fill: packed {src, w} records ----------------
__global__ void fill_csr(const int* __restrict__ src, const int* __restrict__ dst,
                         const float* __restrict__ w, int E,
                         const int* __restrict__ rp, int* __restrict__ cursor,
                         int2* __restrict__ csr) {
    int i = blockIdx.x * blockDim.x + threadIdx.x;
    int stride = gridDim.x * blockDim.x;
    for (int e = i; e < E; e += stride) {
        int d = dst[e];
        int pos = atomicAdd(&cursor[d], 1);
        csr[rp[d] + pos] = make_int2(src[e], __float_as_int(w[e]));
    }
}

// ---------------- per-node: degw = sum w over row -> dinv, dinv2 ----------------
__global__ void rowstats(const int2* __restrict__ csr, const int* __restrict__ rp, int N,
                         float* __restrict__ dinv, float* __restrict__ dinv2) {
    int n = blockIdx.x * blockDim.x + threadIdx.x;
    if (n >= N) return;
    int e = rp[n], end = rp[n + 1];
    float s = 0.f;
    for (; e < end; e++) s += __int_as_float(csr[e].y);
    float d = 1.f + s;
    float r = rsqrtf(d);
    dinv[n] = r;
    dinv2[n] = r * r;
}

// ---------------- per-edge flat: w -> w * dinv[src] ----------------
__global__ void norm_kernel(int2* __restrict__ csr, int E, const float* __restrict__ dinv) {
    int i = blockIdx.x * blockDim.x + threadIdx.x;
    int stride = gridDim.x * blockDim.x;
    for (int e = i; e < E; e += stride) {
        int2 c = csr[e];
        c.y = __float_as_int(__int_as_float(c.y) * dinv[c.x]);
        csr[e] = c;
    }
}

// ---------------- aggregation ----------------
// z[n] = dinv[n] * sum_in (w*dinv[src]) * h[src]  +  dinv2[n] * h[n]
template <int LANES>
__global__ void aggregate_kernel(const float* __restrict__ h, int N,
                                 const int* __restrict__ rp,
                                 const int2* __restrict__ csr,
                                 const float* __restrict__ dinv,
                                 const float* __restrict__ dinv2,
                                 float* __restrict__ z) {
    constexpr int GPB = 256 / LANES;
    int group = threadIdx.x / LANES;
    int lane = threadIdx.x % LANES;
    int n = blockIdx.x * GPB + group;
    if (n >= N) return;
    const float4* h4 = (const float4*)h;
    float4 self = h4[(size_t)n * LANES + lane];
    float4 acc = make_float4(0.f, 0.f, 0.f, 0.f);
    int e = rp[n], end = rp[n + 1];
    for (; e + 3 < end; e += 4) {
        int2 c0 = csr[e], c1 = csr[e + 1], c2 = csr[e + 2], c3 = csr[e + 3];
        float4 v0 = h4[(size_t)c0.x * LANES + lane];
        float4 v1 = h4[(size_t)c1.x * LANES + lane];
        float4 v2 = h4[(size_t)c2.x * LANES + lane];
        float4 v3 = h4[(size_t)c3.x * LANES + lane];
        float n0 = __int_as_float(c0.y), n1 = __int_as_float(c1.y);
        float n2 = __int_as_float(c2.y), n3 = __int_as_float(c3.y);
        acc.x += n0 * v0.x + n1 * v1.x + n2 * v2.x + n3 * v3.x;
        acc.y += n0 * v0.y + n1 * v1.y + n2 * v2.y + n3 * v3.y;
        acc.z += n0 * v0.z + n1 * v1.z + n2 * v2.z + n3 * v3.z;
        acc.w += n0 * v0.w + n1 * v1.w + n2 * v2.w + n3 * v3.w;
    }
    for (; e < end; e++) {
        int2 c = csr[e];
        float nm = __int_as_float(c.y);
        float4 v = h4[(size_t)c.x * LANES + lane];
        acc.x += nm * v.x; acc.y += nm * v.y; acc.z += nm * v.z; acc.w += nm * v.w;
    }
    float di = dinv[n], d2 = dinv2[n];
    float4 o;
    o.x = acc.x * di + self.x * d2;
    o.y = acc.y * di + self.y * d2;
    o.z = acc.z * di + self.z * d2;
    o.w = acc.w * di + self.w * d2;
    float4* z4 = (float4*)z;
    z4[(size_t)n * LANES + lane] = o;
}

// ---------------- GEMM: H[N,128] = relu(Z[N,K] @ W[K,128] + b) ----------------
#define BM 64
#define BK 32
__global__ __launch_bounds__(256) void gemm_bias_relu(
    const float* __restrict__ Z, const float* __restrict__ W,
    const float* __restrict__ bias, float* __restrict__ H, int N, int K) {
    __shared__ __attribute__((aligned(16))) float Wt[BK * 128];
    __shared__ __attribute__((aligned(16))) float Zt[BM * 36];
    int tid = threadIdx.x;
    int row0 = blockIdx.x * BM;
    int j0 = (tid & 31) * 4;
    int r0 = (tid >> 5) * 8;
    float4 acc[8];
    #pragma unroll
    for (int r = 0; r < 8; r++) acc[r] = make_float4(0.f, 0.f, 0.f, 0.f);

    for (int kt = 0; kt < K; kt += BK) {
        #pragma unroll
        for (int i = 0; i < 4; i++) {
            int fid = tid + i * 256;
            int kr = fid >> 5;
            int jc = fid & 31;
            float4 wv = *(const float4*)&W[(size_t)(kt + kr) * 128 + jc * 4];
            *(float4*)&Wt[kr * 128 + jc * 4] = wv;
        }
        #pragma unroll
        for (int i = 0; i < 2; i++) {
            int fid = tid + i * 256;
            int r = fid >> 3;
            int c = fid & 7;
            int gr = row0 + r;
            float4 zv = make_float4(0.f, 0.f, 0.f, 0.f);
            if (gr < N) zv = *(const float4*)&Z[(size_t)gr * K + kt + c * 4];
            *(float4*)&Zt[r * 36 + c * 4] = zv;
        }
        __syncthreads();
        #pragma unroll
        for (int kk = 0; kk < BK; kk++) {
            float4 wv = *(const float4*)&Wt[kk * 128 + j0];
            #pragma unroll
            for (int rr = 0; rr < 8; rr++) {
                float zv = Zt[(r0 + rr) * 36 + kk];
                acc[rr].x += zv * wv.x;
                acc[rr].y += zv * wv.y;
                acc[rr].z += zv * wv.z;
                acc[rr].w += zv * wv.w;
            }
        }
        __syncthreads();
    }
    float4 bv = *(const float4*)&bias[j0];
    #pragma unroll
    for (int rr = 0; rr < 8; rr++) {
        int gr = row0 + r0 + rr;
        if (gr < N) {
            float4 o;
            o.x = fmaxf(acc[rr].x + bv.x, 0.f);
            o.y = fmaxf(acc[rr].y + bv.y, 0.f);
            o.z = fmaxf(acc[rr].z + bv.z, 0.f);
            o.w = fmaxf(acc[rr].w + bv.w, 0.f);
            *(float4*)&H[(size_t)gr * 128 + j0] = o;
        }
    }
}

// ---------------- pooling ----------------
__device__ inline int lower_bound(const int* __restrict__ a, int n, int v) {
    int lo = 0, hi = n;
    while (lo < hi) {
        int m = (lo + hi) >> 1;
        if (a[m] < v) lo = m + 1; else hi = m;
    }
    return lo;
}

__global__ void pool_kernel(const float* __restrict__ hL, const float* __restrict__ hS,
                            const int* __restrict__ batchL, int NL,
                            const int* __restrict__ batchS, int NS,
                            float* __restrict__ pool) {
    int g = blockIdx.x;
    int f = threadIdx.x;  // 128
    int sL = lower_bound(batchL, NL, g), eL = lower_bound(batchL, NL, g + 1);
    int sS = lower_bound(batchS, NS, g), eS = lower_bound(batchS, NS, g + 1);
    float acc = 0.f;
    for (int n = sL; n < eL; n++) acc += hL[(size_t)n * 128 + f];
    for (int n = sS; n < eS; n++) acc += hS[(size_t)n * 128 + f];
    int cnt = (eL - sL) + (eS - sS);
    float c = (float)(cnt > 0 ? cnt : 1);
    pool[g * 128 + f] = acc / c;
}

// ---------------- MLP head ----------------
__global__ void mlp_kernel(const float* __restrict__ pool,
                           const float* __restrict__ W1, const float* __restrict__ b1,
                           const float* __restrict__ W2, const float* __restrict__ b2,
                           const float* __restrict__ gamma, const float* __restrict__ beta,
                           const float* __restrict__ outW, const float* __restrict__ outb,
                           float* __restrict__ d_out) {
    __shared__ float row[128];
    __shared__ float row2[128];
    int g = blockIdx.x, t = threadIdx.x;  // 128 threads
    row[t] = pool[g * 128 + t];
    __syncthreads();
    float a = b1[t];
    #pragma unroll 4
    for (int k = 0; k < 128; k++) a += row[k] * W1[k * 128 + t];
    row2[t] = a;  // no relu between lin1 and lin2 in reference
    __syncthreads();
    if (t < 64) {
        float a2 = b2[t];
        #pragma unroll 4
        for (int k = 0; k < 128; k++) a2 += row2[k] * W2[k * 64 + t];
        float rs = rsqrtf(1.0f + 1e-5f);
        float hb = a2 * rs * gamma[t] + beta[t];
        float hr = fmaxf(hb, 0.f);
        d_out[512 + g * 64 + t] = hr;
        float p = hr * outW[t];
        #pragma unroll
        for (int off = 32; off > 0; off >>= 1) p += __shfl_down(p, off, 64);
        if (t == 0) d_out[g] = p + outb[0];
    }
}

// ---------------------------------------------------------------------------
extern "C" void kernel_launch(void* const* d_in, const int* in_sizes, int n_in,
                              void* d_out, int out_size, void* d_ws, size_t ws_size,
                              hipStream_t stream) {
    const float* x_l = (const float*)d_in[0];
    const int*   ei_l = (const int*)d_in[1];
    const float* w_l = (const float*)d_in[2];
    const float* x_s = (const float*)d_in[3];
    const int*   ei_s = (const int*)d_in[4];
    const float* w_s = (const float*)d_in[5];
    const int*   batch_l = (const int*)d_in[6];
    const int*   batch_s = (const int*)d_in[7];

    const int NL = in_sizes[6];           // 100000
    const int NS = in_sizes[7];           // 50000
    const int EL = in_sizes[2];           // 1600000
    const int ES = in_sizes[5];           // 800000

    const float* Wa[4] = {(const float*)d_in[8],  (const float*)d_in[12],
                          (const float*)d_in[16], (const float*)d_in[20]};
    const float* ba[4] = {(const float*)d_in[9],  (const float*)d_in[13],
                          (const float*)d_in[17], (const float*)d_in[21]};
    const float* Wb[4] = {(const float*)d_in[10], (const float*)d_in[14],
                          (const float*)d_in[18], (const float*)d_in[22]};
    const float* bb[4] = {(const float*)d_in[11], (const float*)d_in[15],
                          (const float*)d_in[19], (const float*)d_in[23]};
    const float* lin1_W = (const float*)d_in[24];
    const float* lin1_b = (const float*)d_in[25];
    const float* lin2_W = (const float*)d_in[26];
    const float* lin2_b = (const float*)d_in[27];
    const float* bn_g = (const float*)d_in[28];
    const float* bn_b = (const float*)d_in[29];
    const float* out_W = (const float*)d_in[30];
    const float* out_b = (const float*)d_in[31];
    float* out = (float*)d_out;

    const int* src_l = ei_l;
    const int* dst_l = ei_l + EL;
    const int* src_s = ei_s;
    const int* dst_s = ei_s + ES;

    // ---- workspace carve ----
    char* p = (char*)d_ws;
    auto alloc = [&](size_t bytes) { char* r = p; p += align256(bytes); return r; };
    float* A_l = (float*)alloc((size_t)NL * 128 * 4);
    float* B_l = (float*)alloc((size_t)NL * 128 * 4);
    float* A_s = (float*)alloc((size_t)NS * 128 * 4);
    float* B_s = (float*)alloc((size_t)NS * 128 * 4);
    int2*  csr_l = (int2*)alloc((size_t)EL * 8);
    int2*  csr_s = (int2*)alloc((size_t)ES * 8);
    int*   rp_l  = (int*)alloc((size_t)(NL + 1) * 4);
    int*   rp_s  = (int*)alloc((size_t)(NS + 1) * 4);
    int*   cnt_l = (int*)alloc((size_t)NL * 4);
    int*   cnt_s = (int*)alloc((size_t)NS * 4);
    float* dinv_l  = (float*)alloc((size_t)NL * 4);
    float* dinv2_l = (float*)alloc((size_t)NL * 4);
    float* dinv_s  = (float*)alloc((size_t)NS * 4);
    float* dinv2_s = (float*)alloc((size_t)NS * 4);
    int*   btot = (int*)alloc(1032 * 4);
    int*   boff = (int*)alloc(1032 * 4);
    float* pool = (float*)alloc((size_t)512 * 128 * 4);
    (void)ws_size; (void)n_in; (void)out_size;

    const int nbL = (NL + 1023) / 1024;
    const int nbS = (NS + 1023) / 1024;

    // ---- counts ----
    hipMemsetAsync(cnt_l, 0, (size_t)NL * 4, stream);
    hipMemsetAsync(cnt_s, 0, (size_t)NS * 4, stream);
    count_kernel<<<2048, 256, 0, stream>>>(dst_l, EL, cnt_l);
    count_kernel<<<1024, 256, 0, stream>>>(dst_s, ES, cnt_s);

    // ---- scan (3-phase) ----
    scan_block<<<nbL, 256, 0, stream>>>(cnt_l, NL, rp_l, btot);
    scan_tot<<<1, 256, 0, stream>>>(btot, nbL, boff);
    scan_add<<<(NL + 255) / 256, 256, 0, stream>>>(rp_l, NL, boff, nbL);
    scan_block<<<nbS, 256, 0, stream>>>(cnt_s, NS, rp_s, btot + 516);
    scan_tot<<<1, 256, 0, stream>>>(btot + 516, nbS, boff + 516);
    scan_add<<<(NS + 255) / 256, 256, 0, stream>>>(rp_s, NS, boff + 516, nbS);

    // ---- CSR fill ----
    hipMemsetAsync(cnt_l, 0, (size_t)NL * 4, stream);  // reuse as cursor
    hipMemsetAsync(cnt_s, 0, (size_t)NS * 4, stream);
    fill_csr<<<2048, 256, 0, stream>>>(src_l, dst_l, w_l, EL, rp_l, cnt_l, csr_l);
    fill_csr<<<1024, 256, 0, stream>>>(src_s, dst_s, w_s, ES, rp_s, cnt_s, csr_s);

    // ---- degree stats + edge norm ----
    rowstats<<<(NL + 255) / 256, 256, 0, stream>>>(csr_l, rp_l, NL, dinv_l, dinv2_l);
    rowstats<<<(NS + 255) / 256, 256, 0, stream>>>(csr_s, rp_s, NS, dinv_s, dinv2_s);
    norm_kernel<<<2048, 256, 0, stream>>>(csr_l, EL, dinv_l);
    norm_kernel<<<1024, 256, 0, stream>>>(csr_s, ES, dinv_s);

    // ---- large branch ----
    aggregate_kernel<16><<<(NL + 15) / 16, 256, 0, stream>>>(
        x_l, NL, rp_l, csr_l, dinv_l, dinv2_l, B_l);
    gemm_bias_relu<<<(NL + BM - 1) / BM, 256, 0, stream>>>(B_l, Wa[0], ba[0], A_l, NL, 64);
    for (int layer = 1; layer < 4; layer++) {
        aggregate_kernel<32><<<(NL + 7) / 8, 256, 0, stream>>>(
            A_l, NL, rp_l, csr_l, dinv_l, dinv2_l, B_l);
        gemm_bias_relu<<<(NL + BM - 1) / BM, 256, 0, stream>>>(B_l, Wa[layer], ba[layer],
                                                               A_l, NL, 128);
    }

    // ---- small branch ----
    aggregate_kernel<8><<<(NS + 31) / 32, 256, 0, stream>>>(
        x_s, NS, rp_s, csr_s, dinv_s, dinv2_s, B_s);
    gemm_bias_relu<<<(NS + BM - 1) / BM, 256, 0, stream>>>(B_s, Wb[0], bb[0], A_s, NS, 32);
    for (int layer = 1; layer < 4; layer++) {
        aggregate_kernel<32><<<(NS + 7) / 8, 256, 0, stream>>>(
            A_s, NS, rp_s, csr_s, dinv_s, dinv2_s, B_s);
        gemm_bias_relu<<<(NS + BM - 1) / BM, 256, 0, stream>>>(B_s, Wb[layer], bb[layer],
                                                               A_s, NS, 128);
    }

    // ---- pooling + head ----
    pool_kernel<<<512, 128, 0, stream>>>(A_l, A_s, batch_l, NL, batch_s, NS, pool);
    mlp_kernel<<<512, 128, 0, stream>>>(pool, lin1_W, lin1_b, lin2_W, lin2_b,
                                        bn_g, bn_b, out_W, out_b, out);
}